// Round 6
// baseline (291.925 us; speedup 1.0000x reference)
//
#include <hip/hip_runtime.h>

#define NUM_LABELS 500
#define NB 8
#define NP (1024 * 1024)
#define BPB 128   // blocks per batch
#define TPB 512
#define NCPY 4    // replicated global-atomic bin copies

// lv_bins is DS-pipe width-bound: 32768 ds_add_u64/CU x 4cy = 54.6 us (R3
// counters match to 1%). This version routes 1 of 4 pixels off the DS pipe
// onto the (idle) L2 atomic path: device-scope u64 atomicAdd into 4
// replicated global bin copies. DS time 0.75x; L2 path overlaps.
//
// Packed u64 fixed-point accumulator per label (both paths):
//   bits [48..63] : count of pixels
//   bits [24..47] : sum of round((v+64)*256), v = sum of 3 channel values
//   bits [0 ..23] : sum of round(q*64), q = sum of 3 channel squares
//
// All persistent state lives in module .bss (zero at load, untouched by the
// harness ws poison); lv_final re-zeroes it after reading (proven R4/R5).

__device__ float g_bins[3 * NB * NUM_LABELS];                  // f32 s/q/c
__device__ unsigned long long g_bins2[NCPY * NB * NUM_LABELS]; // 128 KB

__device__ __forceinline__ unsigned long long lv_pack(float a, float b, float c) {
    float v = a + b + c;
    float q = a * a + b * b + c * c;
    unsigned vf = (unsigned)(fmaf(v, 256.f, 16384.5f));  // (v+64)*256, rounded
    unsigned qf = (unsigned)(fmaf(q, 64.f, 0.5f));       // q*64, rounded
    return (1ULL << 48) | ((unsigned long long)vf << 24) | (unsigned long long)qf;
}

__device__ __forceinline__ void lv_accum(unsigned long long* h, int t,
                                         float a, float b, float c) {
    // Branchless: label-0 pixels land in bin 0, which finalize ignores.
    atomicAdd(&h[t], lv_pack(a, b, c));
}

__global__ __launch_bounds__(TPB) void lv_bins(const float* __restrict__ x,
                                               const int* __restrict__ tgt) {
    // 2 histogram copies: even waves use h[0..499], odd waves h[500..999].
    __shared__ unsigned long long h[2 * NUM_LABELS];

    const int b = blockIdx.y;
    for (int i = threadIdx.x; i < 2 * NUM_LABELS; i += TPB) h[i] = 0ULL;
    __syncthreads();

    unsigned long long* hw = h + ((threadIdx.x >> 6) & 1) * NUM_LABELS;
    unsigned long long* g2 =
        g_bins2 + ((size_t)((blockIdx.x & (NCPY - 1)) * NB + b)) * NUM_LABELS;

    const float* x0 = x + (size_t)(b * 3 + 0) * NP;
    const float* x1 = x + (size_t)(b * 3 + 1) * NP;
    const float* x2 = x + (size_t)(b * 3 + 2) * NP;
    const int*   tg = tgt + (size_t)b * NP;

    const int pixPerBlock = NP / BPB;           // 8192
    const int stride = TPB * 4;                 // 2048
    const int nIter = pixPerBlock / stride;     // 4

    int p = blockIdx.x * pixPerBlock + (int)threadIdx.x * 4;

    // software-pipelined: next iteration's loads issue before current atomics
    int4   t4 = *(const int4*)(tg + p);
    float4 a4 = *(const float4*)(x0 + p);
    float4 b4 = *(const float4*)(x1 + p);
    float4 c4 = *(const float4*)(x2 + p);

    for (int it = 0; it < nIter - 1; ++it) {
        const int pn = p + stride;
        int4   tn = *(const int4*)(tg + pn);
        float4 an = *(const float4*)(x0 + pn);
        float4 bn = *(const float4*)(x1 + pn);
        float4 cn = *(const float4*)(x2 + pn);

        lv_accum(hw, t4.x, a4.x, b4.x, c4.x);
        lv_accum(hw, t4.y, a4.y, b4.y, c4.y);
        lv_accum(hw, t4.z, a4.z, b4.z, c4.z);
        atomicAdd(&g2[t4.w], lv_pack(a4.w, b4.w, c4.w));  // L2 path

        t4 = tn; a4 = an; b4 = bn; c4 = cn;
        p = pn;
    }
    lv_accum(hw, t4.x, a4.x, b4.x, c4.x);
    lv_accum(hw, t4.y, a4.y, b4.y, c4.y);
    lv_accum(hw, t4.z, a4.z, b4.z, c4.z);
    atomicAdd(&g2[t4.w], lv_pack(a4.w, b4.w, c4.w));      // L2 path

    __syncthreads();

    float* g_s = g_bins;
    float* g_q = g_bins + NB * NUM_LABELS;
    float* g_c = g_bins + 2 * NB * NUM_LABELS;
    for (int i = threadIdx.x; i < NUM_LABELS; i += TPB) {
        unsigned long long w = h[i] + h[NUM_LABELS + i];
        if (w != 0ULL) {
            float cnt = (float)(unsigned)(w >> 48);
            float sv  = (float)(unsigned)((w >> 24) & 0xFFFFFFu) * (1.f / 256.f)
                        - 64.f * cnt;
            float sq  = (float)(unsigned)(w & 0xFFFFFFu) * (1.f / 64.f);
            atomicAdd(&g_s[b * NUM_LABELS + i], sv);
            atomicAdd(&g_q[b * NUM_LABELS + i], sq);
            atomicAdd(&g_c[b * NUM_LABELS + i], cnt);
        }
    }
}

// Finalize: 8 waves, wave b reduces batch b over labels 1..499, merging the
// f32 bins (LDS path) with the 4 replicated u64 copies (L2 path), then
// re-zeroes all .bss state for the next graph replay.
__global__ __launch_bounds__(512) void lv_final(float* __restrict__ out) {
    const int wave = threadIdx.x >> 6;
    const int lane = threadIdx.x & 63;

    const float* g_s = g_bins;
    const float* g_q = g_bins + NB * NUM_LABELS;
    const float* g_c = g_bins + 2 * NB * NUM_LABELS;

    float var_sum = 0.f;
    float uniq = 0.f;
    for (int l = 1 + lane; l < NUM_LABELS; l += 64) {
        float c = g_c[wave * NUM_LABELS + l];
        float s = g_s[wave * NUM_LABELS + l];
        float q = g_q[wave * NUM_LABELS + l];
        // merge L2-path copies (unpack per copy; zero after read — each
        // element is read by exactly one lane)
#pragma unroll
        for (int cp = 0; cp < NCPY; ++cp) {
            const size_t idx = (size_t)(cp * NB + wave) * NUM_LABELS + l;
            unsigned long long w = g_bins2[idx];
            g_bins2[idx] = 0ULL;
            float c2 = (float)(unsigned)(w >> 48);
            c += c2;
            s += (float)(unsigned)((w >> 24) & 0xFFFFFFu) * (1.f / 256.f)
                 - 64.f * c2;
            q += (float)(unsigned)(w & 0xFFFFFFu) * (1.f / 64.f);
        }
        if (c > 0.f) uniq += 1.f;
        if (c > 1.f) {
            float N = 3.f * c;
            var_sum += (q - s * s / N) / (N - 1.f);
        }
    }
    // zero the never-read label-0 slots (hygiene: avoid unbounded growth)
    if (lane == 0) {
#pragma unroll
        for (int cp = 0; cp < NCPY; ++cp)
            g_bins2[(size_t)(cp * NB + wave) * NUM_LABELS] = 0ULL;
    }

    for (int off = 32; off > 0; off >>= 1) {
        var_sum += __shfl_down(var_sum, off);
        uniq    += __shfl_down(uniq, off);
    }

    __shared__ float part[NB];
    if (lane == 0) part[wave] = var_sum / (uniq + 1e-8f);
    __syncthreads();   // all reads of g_bins complete before re-zeroing

    // Re-zero f32 bins for the next replay (12000 floats).
    for (int i = threadIdx.x; i < 3 * NB * NUM_LABELS; i += 512)
        g_bins[i] = 0.f;

    if (threadIdx.x == 0) {
        float acc = 0.f;
        for (int i = 0; i < NB; ++i) acc += part[i];
        out[0] = acc * (1.f / NB);
    }
}

extern "C" void kernel_launch(void* const* d_in, const int* in_sizes, int n_in,
                              void* d_out, int out_size, void* d_ws, size_t ws_size,
                              hipStream_t stream) {
    const float* x   = (const float*)d_in[0];
    const int*   tgt = (const int*)d_in[1];
    float*       out = (float*)d_out;

    dim3 grid(BPB, NB);
    lv_bins<<<grid, TPB, 0, stream>>>(x, tgt);
    lv_final<<<1, 512, 0, stream>>>(out);
}

// Round 7
// 178.326 us; speedup vs baseline: 1.6370x; 1.6370x over previous
//
#include <hip/hip_runtime.h>

#define NUM_LABELS 500
#define NB 8
#define NP (1024 * 1024)
#define BPB 128   // blocks per batch
#define TPB 512

// Champion structure (R5: 179.77 us). lv_bins is DS-pipe width-bound:
// 32768 ds_add_u64/CU x 4 cy = 54.6 us, confirmed by R3 counters to 1%.
// Offload attempts (global f32 atomics, global u64 atomics, in-kernel
// fusion) all measured worse; this is the structural floor.
//
//  - bins live in module .bss (zero at load, NOT touched by the harness's
//    384 MiB d_ws poison fill), so no pre-zeroing dispatch is needed;
//  - lv_final re-zeroes bins after reading them, so every graph replay
//    starts from zeros (visibility via standard inter-dispatch ordering).
//
// Packed u64 fixed-point accumulator per label in LDS (2 copies, even/odd
// waves, halves same-address ds_add_u64 serialization):
//   bits [48..63] : count of pixels
//   bits [24..47] : sum of round((v+64)*256), v = sum of 3 channel values
//   bits [0 ..23] : sum of round(q*64), q = sum of 3 channel squares
// One ds_add_u64 per pixel; per-block flush via global f32 atomics into
// 12 KB of L2-hot bins; tiny finalize kernel reads 6 KB then re-zeroes.

__device__ float g_bins[3 * NB * NUM_LABELS];   // .bss → zero at module load

__device__ __forceinline__ void lv_accum(unsigned long long* h, int t,
                                         float a, float b, float c) {
    // Branchless: label-0 pixels land in h[0], which finalize ignores
    // (reference drops label 0).
    float v = a + b + c;
    float q = a * a + b * b + c * c;
    unsigned vf = (unsigned)(fmaf(v, 256.f, 16384.5f));  // (v+64)*256, rounded
    unsigned qf = (unsigned)(fmaf(q, 64.f, 0.5f));       // q*64, rounded
    unsigned long long pk =
        (1ULL << 48) | ((unsigned long long)vf << 24) | (unsigned long long)qf;
    atomicAdd(&h[t], pk);
}

__global__ __launch_bounds__(TPB) void lv_bins(const float* __restrict__ x,
                                               const int* __restrict__ tgt) {
    // 2 histogram copies: even waves use h[0..499], odd waves h[500..999].
    __shared__ unsigned long long h[2 * NUM_LABELS];

    const int b = blockIdx.y;
    for (int i = threadIdx.x; i < 2 * NUM_LABELS; i += TPB) h[i] = 0ULL;
    __syncthreads();

    unsigned long long* hw = h + ((threadIdx.x >> 6) & 1) * NUM_LABELS;

    const float* x0 = x + (size_t)(b * 3 + 0) * NP;
    const float* x1 = x + (size_t)(b * 3 + 1) * NP;
    const float* x2 = x + (size_t)(b * 3 + 2) * NP;
    const int*   tg = tgt + (size_t)b * NP;

    const int pixPerBlock = NP / BPB;           // 8192
    const int stride = TPB * 4;                 // 2048
    const int nIter = pixPerBlock / stride;     // 4

    int p = blockIdx.x * pixPerBlock + (int)threadIdx.x * 4;

    // software-pipelined: next iteration's loads issue before current atomics
    int4   t4 = *(const int4*)(tg + p);
    float4 a4 = *(const float4*)(x0 + p);
    float4 b4 = *(const float4*)(x1 + p);
    float4 c4 = *(const float4*)(x2 + p);

    for (int it = 0; it < nIter - 1; ++it) {
        const int pn = p + stride;
        int4   tn = *(const int4*)(tg + pn);
        float4 an = *(const float4*)(x0 + pn);
        float4 bn = *(const float4*)(x1 + pn);
        float4 cn = *(const float4*)(x2 + pn);

        lv_accum(hw, t4.x, a4.x, b4.x, c4.x);
        lv_accum(hw, t4.y, a4.y, b4.y, c4.y);
        lv_accum(hw, t4.z, a4.z, b4.z, c4.z);
        lv_accum(hw, t4.w, a4.w, b4.w, c4.w);

        t4 = tn; a4 = an; b4 = bn; c4 = cn;
        p = pn;
    }
    lv_accum(hw, t4.x, a4.x, b4.x, c4.x);
    lv_accum(hw, t4.y, a4.y, b4.y, c4.y);
    lv_accum(hw, t4.z, a4.z, b4.z, c4.z);
    lv_accum(hw, t4.w, a4.w, b4.w, c4.w);

    __syncthreads();

    float* g_s = g_bins;
    float* g_q = g_bins + NB * NUM_LABELS;
    float* g_c = g_bins + 2 * NB * NUM_LABELS;
    for (int i = threadIdx.x; i < NUM_LABELS; i += TPB) {
        unsigned long long w = h[i] + h[NUM_LABELS + i];
        if (w != 0ULL) {
            float cnt = (float)(unsigned)(w >> 48);
            float sv  = (float)(unsigned)((w >> 24) & 0xFFFFFFu) * (1.f / 256.f)
                        - 64.f * cnt;
            float sq  = (float)(unsigned)(w & 0xFFFFFFu) * (1.f / 64.f);
            atomicAdd(&g_s[b * NUM_LABELS + i], sv);
            atomicAdd(&g_q[b * NUM_LABELS + i], sq);
            atomicAdd(&g_c[b * NUM_LABELS + i], cnt);
        }
    }
}

// Finalize: 8 waves, wave b reduces batch b over labels 1..499 (6 KB, L2-hot),
// then the block re-zeroes g_bins for the next graph replay.
__global__ __launch_bounds__(512) void lv_final(float* __restrict__ out) {
    const int wave = threadIdx.x >> 6;
    const int lane = threadIdx.x & 63;

    const float* g_s = g_bins;
    const float* g_q = g_bins + NB * NUM_LABELS;
    const float* g_c = g_bins + 2 * NB * NUM_LABELS;

    float var_sum = 0.f;
    float uniq = 0.f;
    for (int l = 1 + lane; l < NUM_LABELS; l += 64) {
        float c = g_c[wave * NUM_LABELS + l];
        float s = g_s[wave * NUM_LABELS + l];
        float q = g_q[wave * NUM_LABELS + l];
        if (c > 0.f) uniq += 1.f;
        if (c > 1.f) {
            float N = 3.f * c;
            var_sum += (q - s * s / N) / (N - 1.f);
        }
    }
    for (int off = 32; off > 0; off >>= 1) {
        var_sum += __shfl_down(var_sum, off);
        uniq    += __shfl_down(uniq, off);
    }

    __shared__ float part[NB];
    if (lane == 0) part[wave] = var_sum / (uniq + 1e-8f);
    __syncthreads();   // all reads of g_bins complete before re-zeroing

    // Re-zero bins for the next replay (12000 floats, ~24 stores/thread).
    for (int i = threadIdx.x; i < 3 * NB * NUM_LABELS; i += 512)
        g_bins[i] = 0.f;

    if (threadIdx.x == 0) {
        float acc = 0.f;
        for (int i = 0; i < NB; ++i) acc += part[i];
        out[0] = acc * (1.f / NB);
    }
}

extern "C" void kernel_launch(void* const* d_in, const int* in_sizes, int n_in,
                              void* d_out, int out_size, void* d_ws, size_t ws_size,
                              hipStream_t stream) {
    const float* x   = (const float*)d_in[0];
    const int*   tgt = (const int*)d_in[1];
    float*       out = (float*)d_out;

    dim3 grid(BPB, NB);
    lv_bins<<<grid, TPB, 0, stream>>>(x, tgt);
    lv_final<<<1, 512, 0, stream>>>(out);
}